// Round 14
// baseline (197.931 us; speedup 1.0000x reference)
//
#include <hip/hip_runtime.h>
#include <math.h>

// Problem dims (fixed): B=128, S=64, H=128, STATIC=DYNAMIC=2
// Outputs: tour_idx [B,S] (as f32), tour_logp [B,S] -> d_out 16384 f32

#define K1  1.44269504088896340736f   // log2(e)
#define K2  2.88539008177792681472f   // 2*log2(e)
#define LN2 0.69314718055994530942f

// ---------------- ws layout (float offsets) ----------------
#define WS_M     0                       // [384][2]   M = wih @ decoder_w
#define WS_C     768                     // [384]      c = wih @ decoder_b + bih
#define WS_PREA  1152                    // [B][128][64] EA = exp2(K2*(W1@sh + W2@dh))
#define WS_PREP  (WS_PREA + 128*8192)    // [B][128][64] EP = exp2(K2*(P1@sh))
#define WS_Q     (WS_PREP + 128*8192)    // [B][128][64] Q  = P2@sh

// ---- DPP cross-lane (VALU-speed) ----
template <int CTRL>
__device__ __forceinline__ float dppk(float x) {  // bound_ctrl=0: keep self
  int xi = __builtin_bit_cast(int, x);
  return __builtin_bit_cast(float,
      __builtin_amdgcn_update_dpp(xi, xi, CTRL, 0xF, 0xF, false));
}
template <int CTRL>
__device__ __forceinline__ float dppz(float x) {  // bound_ctrl=1: zero-fill
  int xi = __builtin_bit_cast(int, x);
  return __builtin_bit_cast(float,
      __builtin_amdgcn_update_dpp(0, xi, CTRL, 0xF, 0xF, true));
}
__device__ __forceinline__ float bcastf(float x, int lane) {
  return __builtin_bit_cast(float,
      __builtin_amdgcn_readlane(__builtin_bit_cast(int, x), lane));
}
// 0xB1=quad xor1, 0x4E=quad xor2, 0x141=row_half_mirror, 0x128=row_ror:8
__device__ __forceinline__ float sum4(float x) {
  x += dppk<0xB1>(x); x += dppk<0x4E>(x); return x;
}
__device__ __forceinline__ float sum16(float x) {  // 16-lane rows
  x += dppk<0xB1>(x); x += dppk<0x4E>(x); x += dppk<0x141>(x); x += dppk<0x128>(x);
  return x;
}
// wave64 prefix reductions (row_shr + row_bcast + readlane, zero LDS)
__device__ __forceinline__ float wsum64(float x) {
  x += dppz<0x111>(x); x += dppz<0x112>(x); x += dppz<0x114>(x);
  x += dppz<0x118>(x); x += dppz<0x142>(x); x += dppz<0x143>(x);
  return bcastf(x, 63);
}
__device__ __forceinline__ float wmax64(float x) {
  x = fmaxf(x, dppk<0x111>(x)); x = fmaxf(x, dppk<0x112>(x));
  x = fmaxf(x, dppk<0x114>(x)); x = fmaxf(x, dppk<0x118>(x));
  x = fmaxf(x, dppk<0x142>(x)); x = fmaxf(x, dppk<0x143>(x));
  return bcastf(x, 63);
}
#define RCP(x)  __builtin_amdgcn_rcpf(x)
#define EXP2(x) __builtin_amdgcn_exp2f(x)

// lgkm-only barrier (no vmcnt drain)
__device__ __forceinline__ void bar_lds() {
  asm volatile("s_waitcnt lgkmcnt(0)" ::: "memory");
  __builtin_amdgcn_s_barrier();
  asm volatile("" ::: "memory");
}

// bijective bank-rotation for pair-granule index p
__device__ __forceinline__ int rot8(int p) {
  return (p & 56) | ((p + (p >> 3)) & 7);
}

// ---------------- tiny precompute: GRU input-path folding ----------------
__global__ __launch_bounds__(256) void prep_small(
    const float* __restrict__ wih, const float* __restrict__ decw,
    const float* __restrict__ decb, const float* __restrict__ bih,
    float* __restrict__ ws) {
  int gid = blockIdx.x * 256 + threadIdx.x;
  if (gid < 384) {
    float m0 = 0.f, m1 = 0.f, cc = 0.f;
    for (int k = 0; k < 128; ++k) {
      float w = wih[gid * 128 + k];
      m0 += w * decw[k * 2 + 0];
      m1 += w * decw[k * 2 + 1];
      cc += w * decb[k];
    }
    ws[WS_M + gid * 2 + 0] = m0;
    ws[WS_M + gid * 2 + 1] = m1;
    ws[WS_C + gid] = cc + bih[gid];
  }
}

// ---------------- big precompute: EA / EP / Q per batch ------------------
__global__ __launch_bounds__(256) void prep_big(
    const float* __restrict__ statics, const float* __restrict__ dynamics,
    const float* __restrict__ sw, const float* __restrict__ sb,
    const float* __restrict__ dw, const float* __restrict__ db,
    const float* __restrict__ attn_W, const float* __restrict__ ptr_W,
    float* __restrict__ ws) {
  __shared__ __align__(16) float sh[128 * 64];
  __shared__ __align__(16) float dh[128 * 64];
  __shared__ float st[128];
  __shared__ float dy[128];
  int b = blockIdx.x >> 3;
  int hq = blockIdx.x & 7;
  int t = threadIdx.x;
  if (t < 128) st[t] = statics[b * 128 + t];
  else         dy[t - 128] = dynamics[b * 128 + (t - 128)];
  __syncthreads();
  for (int e = t; e < 8192; e += 256) {
    int h = e >> 6, s = e & 63;
    sh[e] = sw[h * 2 + 0] * st[s] + sw[h * 2 + 1] * st[64 + s] + sb[h];
    dh[e] = dw[h * 2 + 0] * dy[s] + dw[h * 2 + 1] * dy[64 + s] + db[h];
  }
  __syncthreads();
  int hh = hq * 16 + (t >> 4);
  int s0 = (t & 15) * 4;
  float4 pA = {0, 0, 0, 0}, pP = {0, 0, 0, 0}, qq = {0, 0, 0, 0};
  for (int k = 0; k < 128; ++k) {
    float4 sv = *(const float4*)&sh[k * 64 + s0];
    float4 dv = *(const float4*)&dh[k * 64 + s0];
    float w1 = attn_W[hh * 384 + k];
    float w2 = attn_W[hh * 384 + 128 + k];
    float p1 = ptr_W[hh * 256 + k];
    float p2 = ptr_W[hh * 256 + 128 + k];
    pA.x += w1 * sv.x + w2 * dv.x;  pA.y += w1 * sv.y + w2 * dv.y;
    pA.z += w1 * sv.z + w2 * dv.z;  pA.w += w1 * sv.w + w2 * dv.w;
    pP.x += p1 * sv.x;  pP.y += p1 * sv.y;  pP.z += p1 * sv.z;  pP.w += p1 * sv.w;
    qq.x += p2 * sv.x;  qq.y += p2 * sv.y;  qq.z += p2 * sv.z;  qq.w += p2 * sv.w;
  }
  // store exp-transformed score bases (shared-exp tanh trick)
  float4 eA, eP;
  eA.x = exp2f(K2 * pA.x); eA.y = exp2f(K2 * pA.y);
  eA.z = exp2f(K2 * pA.z); eA.w = exp2f(K2 * pA.w);
  eP.x = exp2f(K2 * pP.x); eP.y = exp2f(K2 * pP.y);
  eP.z = exp2f(K2 * pP.z); eP.w = exp2f(K2 * pP.w);
  int o = b * 8192 + hh * 64 + s0;
  *(float4*)&ws[WS_PREA + o] = eA;
  *(float4*)&ws[WS_PREP + o] = eP;
  *(float4*)&ws[WS_Q + o]    = qq;
}

// ---------------- main recurrence: 1 block/batch, 512 thr, 64 steps -----
// Round-14 = round-13 + score-phase remap: lane = (hgx = lane&15 owning 8 h,
// sq = lane>>4 owning 2 s).  Same 16 rcp/lane but uav reads 8->4 and EAT/EPT
// reads stay 4 with h-runs doubled => PC 13->9, PE 9->5 LDS instr (-15%
// block LDS issue).  All new patterns position-audited to 2 lanes/position
// with distinct addresses (free per m136).  uav layout/writers unchanged.
__global__ __launch_bounds__(512)
__attribute__((amdgpu_waves_per_eu(2)))
void drl4tsp_main(
    const float* __restrict__ statics, const float* __restrict__ x0,
    const float* __restrict__ whh, const float* __restrict__ attn_W,
    const float* __restrict__ bhh_g, const float* __restrict__ attn_v,
    const float* __restrict__ ptr_v, const float* __restrict__ ws,
    float* __restrict__ out) {
  __shared__ float4 W3s4[128 * 32];   // 64KB [g][(j+2g)&31]
  __shared__ float4 EAT4[64 * 32];    // 32KB [s][perm(gi)+16*((s>>1)&1)]
  __shared__ float4 EPT4[64 * 32];    // 32KB
  __shared__ float4 uav3[64];         // {u3f,av2} pairs @ rot8(p)
  __shared__ float4 uav2[64];         // {u2f,pv2} pairs @ rot8(p)
  __shared__ float4 gp4[128 * 3];     // 6KB gate params
  __shared__ __align__(16) float hp[144];     // h padded: [k>>5]*36 + (k&31)
  __shared__ __align__(16) float attns[64];   // shared e-buffer
  __shared__ __align__(16) float a_lds[64];
  __shared__ __align__(16) float l_lds[64];
  __shared__ float stt[128];
  __shared__ float outbuf[64];        // per-step argmax idx
  __shared__ float Lhist[4096];       // 16KB: logits archive [step][s]

  const int b    = blockIdx.x;
  const int t    = threadIdx.x;
  const int lane = t & 63;
  const int g    = t >> 2;   // 0..127 row (matvec map, 4-lane groups)
  const int q    = t & 3;    // k quarter
  const int hgx  = lane & 15;          // score map: h-group of 8
  const int sq   = lane >> 4;          // score map: s-pair within window
  const int s0   = (t >> 6) * 8 + sq * 2;  // this lane's first s
  const int posb = (hgx + ((sq & 1) << 4)) & 31;  // EAT/EPT j=0 position

  // ---- register weights: whh rows, interleaved k-map (k = kk*16+q*4+j) ----
  float wr0[32], wr1[32], wr2[32];
#pragma unroll
  for (int kk = 0; kk < 8; ++kk) {
    float4 a = *(const float4*)(whh + g * 128         + kk * 16 + q * 4);
    float4 c = *(const float4*)(whh + (128 + g) * 128 + kk * 16 + q * 4);
    float4 d = *(const float4*)(whh + (256 + g) * 128 + kk * 16 + q * 4);
    wr0[4*kk] = a.x; wr0[4*kk+1] = a.y; wr0[4*kk+2] = a.z; wr0[4*kk+3] = a.w;
    wr1[4*kk] = c.x; wr1[4*kk+1] = c.y; wr1[4*kk+2] = c.z; wr1[4*kk+3] = c.w;
    wr2[4*kk] = d.x; wr2[4*kk+1] = d.y; wr2[4*kk+2] = d.z; wr2[4*kk+3] = d.w;
  }
  float qr[16];
  {
    const float4* pq = (const float4*)(ws + WS_Q + b * 8192 + g * 64 + q * 16);
#pragma unroll
    for (int i = 0; i < 4; ++i) {
      float4 v = pq[i];
      qr[4*i] = v.x; qr[4*i+1] = v.y; qr[4*i+2] = v.z; qr[4*i+3] = v.w;
    }
  }

  // ---- LDS init ----
  {  // W3 row g, granule j stored at (j+2g)&31 (2-way-free rotation)
    const float4* src = (const float4*)(attn_W + g * 384 + 256);
#pragma unroll
    for (int kk = 0; kk < 8; ++kk) {
      int j = q * 8 + kk;
      W3s4[g * 32 + ((j + 2 * g) & 31)] = src[j];
    }
  }
  for (int e = t; e < 8192; e += 512) {  // EA/EP: perm(gi) + s-rotation
    int h = e >> 6, sE = e & 63;
    int gi = h >> 2;
    int pos = ((gi >> 1) + ((gi & 1) << 4) + (((sE >> 1) & 1) << 4)) & 31;
    int idx = sE * 128 + pos * 4 + (h & 3);
    ((float*)EAT4)[idx] = ws[WS_PREA + b * 8192 + e];
    ((float*)EPT4)[idx] = ws[WS_PREP + b * 8192 + e];
  }
  if (t < 128) {
    int h = t;
    int rg = rot8(h >> 1);
    ((float*)uav3)[rg * 4 + (h & 1) * 2 + 1] = 2.0f * attn_v[h];
    ((float*)uav2)[rg * 4 + (h & 1) * 2 + 1] = 2.0f * ptr_v[h];
    stt[h] = statics[b * 128 + h];
    const float* Mm = ws + WS_M;
    const float* Cc = ws + WS_C;
    float cR = Cc[h] + bhh_g[h];
    float cZ = Cc[128 + h] + bhh_g[128 + h];
    gp4[h*3 + 0] = float4{Mm[h*2], Mm[h*2+1], cR, Mm[(128+h)*2]};
    gp4[h*3 + 1] = float4{Mm[(128+h)*2+1], cZ, Mm[(256+h)*2], Mm[(256+h)*2+1]};
    gp4[h*3 + 2] = float4{Cc[256+h], bhh_g[256+h], 0.f, 0.f};
  }
  __syncthreads();

  float hreg = 0.f, ghr = 0.f, ghz = 0.f, ghn = 0.f;
  float d0 = x0[0], d1 = x0[1];

  for (int step = 0; step < 64; ++step) {
    // ---- P1: GRU gates (pointwise; gh carried from prev step) ----
    {
      float4 v0 = gp4[g*3], v1 = gp4[g*3+1], v2 = gp4[g*3+2];
      float r = RCP(1.f + EXP2(-K1 * (v0.x*d0 + v0.y*d1 + v0.z + ghr)));
      float z = RCP(1.f + EXP2(-K1 * (v0.w*d0 + v1.x*d1 + v1.y + ghz)));
      float xn = v1.z*d0 + v1.w*d1 + v2.x + r * (ghn + v2.y);
      float n = 1.f - 2.f * RCP(EXP2(K2 * xn) + 1.f);   // tanh(xn)
      hreg = (1.f - z) * n + z * hreg;
      if (q == 0) hp[(g >> 5) * 36 + (g & 31)] = hreg;
    }
    bar_lds();                                         // A
    // ---- PB: u3 = W3@h only (gh matvec deferred to C/D windows) ----
    {
      float u3a = 0.f, u3b = 0.f;
#pragma unroll
      for (int kk = 0; kk < 8; ++kk) {
        float4 hv = *(const float4*)&hp[(kk >> 1) * 36 + (kk & 1) * 16 + q * 4];
        float4 wv = W3s4[g * 32 + ((kk * 4 + q + 2 * g) & 31)];
        float d2 = wv.x*hv.x + wv.y*hv.y + wv.z*hv.z + wv.w*hv.w;
        if (kk & 1) u3b += d2; else u3a += d2;
      }
      float u3 = sum4(u3a + u3b);
      if (q == 0)
        ((float*)uav3)[rot8(g >> 1) * 4 + (g & 1) * 2] = EXP2(K2 * u3);
    }
    bar_lds();                                         // B
    float sr = 0.f, sz = 0.f, sn = 0.f;   // gh partials, finalized in PD
    // ---- PC: attn scores (hgx/sq map) + gh kk=0..3 (independent fill) --
    {
      float acc0 = 0.f, acc1 = 0.f;
#pragma unroll
      for (int j = 0; j < 2; ++j) {
        float4 uvA = uav3[rot8(hgx * 4 + 2 * j)];
        float4 uvB = uav3[rot8(hgx * 4 + 2 * j + 1)];
        int pos = (posb + 16 * j) & 31;
#pragma unroll
        for (int ss = 0; ss < 2; ++ss) {
          float4 ea = EAT4[(s0 + ss) * 32 + pos];
          float x1 = ea.x * uvA.x + 1.f, y1 = ea.y * uvA.z + 1.f;
          float x2 = ea.z * uvB.x + 1.f, y2 = ea.w * uvB.z + 1.f;
          float r1 = (uvA.y * y1 + uvA.w * x1) * RCP(x1 * y1);
          float r2 = (uvB.y * y2 + uvB.w * x2) * RCP(x2 * y2);
          if (ss == 0) acc0 += r1 + r2; else acc1 += r1 + r2;
        }
      }
#pragma unroll
      for (int kk = 0; kk < 4; ++kk) {
        float4 hv = *(const float4*)&hp[(kk >> 1) * 36 + (kk & 1) * 16 + q * 4];
        int k = kk * 4;
        sr += wr0[k]*hv.x + wr0[k+1]*hv.y + wr0[k+2]*hv.z + wr0[k+3]*hv.w;
        sz += wr1[k]*hv.x + wr1[k+1]*hv.y + wr1[k+2]*hv.z + wr1[k+3]*hv.w;
        sn += wr2[k]*hv.x + wr2[k+1]*hv.y + wr2[k+2]*hv.z + wr2[k+3]*hv.w;
      }
      acc0 = sum16(acc0);
      acc1 = sum16(acc1);
      if (hgx == 0) *(float2*)&a_lds[s0] = float2{-acc0, -acc1};
    }
    bar_lds();                                         // C
    // ---- PD: softmax (no max-shift) + u2 = Q@attns + gh kk=4..7
    //          + EPT prefetch for PE (issued under the softmax chain) ----
    float4 ep0, ep1, ep2, ep3;
    {
      float a = a_lds[lane];
      ep0 = EPT4[(s0 + 0) * 32 + posb];                 // j=0
      ep1 = EPT4[(s0 + 1) * 32 + posb];
      ep2 = EPT4[(s0 + 0) * 32 + ((posb + 16) & 31)];   // j=1
      ep3 = EPT4[(s0 + 1) * 32 + ((posb + 16) & 31)];
      float e = EXP2(K1 * a);          // |a| <~ 20 -> range-safe in f32
      attns[lane] = e;                 // identical writes from all waves
#pragma unroll
      for (int kk = 4; kk < 8; ++kk) { // fill attns write->read latency
        float4 hv = *(const float4*)&hp[(kk >> 1) * 36 + (kk & 1) * 16 + q * 4];
        int k = kk * 4;
        sr += wr0[k]*hv.x + wr0[k+1]*hv.y + wr0[k+2]*hv.z + wr0[k+3]*hv.w;
        sz += wr1[k]*hv.x + wr1[k+1]*hv.y + wr1[k+2]*hv.z + wr1[k+3]*hv.w;
        sn += wr2[k]*hv.x + wr2[k+1]*hv.y + wr2[k+2]*hv.z + wr2[k+3]*hv.w;
      }
      float sum = wsum64(e);           // all-DPP prefix + readlane (uniform)
      float p = 0.f;
#pragma unroll
      for (int ii = 0; ii < 4; ++ii) {
        float4 av = *(const float4*)&attns[q * 16 + ii * 4];
        p += qr[4*ii]*av.x + qr[4*ii+1]*av.y + qr[4*ii+2]*av.z + qr[4*ii+3]*av.w;
      }
      p *= RCP(sum);
      p = sum4(p);
      if (q == 0)
        ((float*)uav2)[rot8(g >> 1) * 4 + (g & 1) * 2] = EXP2(K2 * p);
      ghr = sum4(sr); ghz = sum4(sz); ghn = sum4(sn);
    }
    bar_lds();                                         // D
    // ---- PE: ptr logits (hgx/sq map, EPT prefetched) ----
    {
      float acc0 = 0.f, acc1 = 0.f;
#pragma unroll
      for (int j = 0; j < 2; ++j) {
        float4 uvA = uav2[rot8(hgx * 4 + 2 * j)];
        float4 uvB = uav2[rot8(hgx * 4 + 2 * j + 1)];
#pragma unroll
        for (int ss = 0; ss < 2; ++ss) {
          float4 ep = (j == 0) ? (ss == 0 ? ep0 : ep1)
                               : (ss == 0 ? ep2 : ep3);
          float x1 = ep.x * uvA.x + 1.f, y1 = ep.y * uvA.z + 1.f;
          float x2 = ep.z * uvB.x + 1.f, y2 = ep.w * uvB.z + 1.f;
          float r1 = (uvA.y * y1 + uvA.w * x1) * RCP(x1 * y1);
          float r2 = (uvB.y * y2 + uvB.w * x2) * RCP(x2 * y2);
          if (ss == 0) acc0 += r1 + r2; else acc1 += r1 + r2;
        }
      }
      acc0 = sum16(acc0);
      acc1 = sum16(acc1);
      if (hgx == 0) *(float2*)&l_lds[s0] = float2{-acc0, -acc1};
    }
    bar_lds();                                         // E
    // ---- P6: argmax only (logp deferred); DPP max + ballot/ctz ----
    {
      float L = l_lds[lane];
      float v = wmax64(L);                        // uniform via readlane
      unsigned long long mk = __ballot(L == v);   // exact bit-compare
      int idx = __builtin_ctzll(mk);              // lowest lane = lowest s
      if (t < 64) Lhist[step * 64 + t] = L;       // archive for logp pass
      if (t == 0) outbuf[step] = (float)idx;
      d0 = stt[idx];                              // uniform broadcast
      d1 = stt[64 + idx];
    }
    // no barrier: every buffer's next write is >=2 barrier-phases away
  }
  bar_lds();
  // ---- epilogue: all 64 log-softmax values in parallel (8 waves x 8) ----
  {
    int wv = t >> 6;
    for (int st = wv; st < 64; st += 8) {
      float L = Lhist[st * 64 + lane];
      float v = wmax64(L);
      float e2 = EXP2(K1 * (L - v));
      float s3 = wsum64(e2);
      if (lane == 0)
        out[8192 + b * 64 + st] = -LN2 * __builtin_amdgcn_logf(s3);
      if (lane == 1)
        out[b * 64 + st] = outbuf[st];
    }
  }
}

extern "C" void kernel_launch(void* const* d_in, const int* in_sizes, int n_in,
                              void* d_out, int out_size, void* d_ws, size_t ws_size,
                              hipStream_t stream) {
  const float* statics  = (const float*)d_in[0];
  const float* dynamics = (const float*)d_in[1];
  const float* x0       = (const float*)d_in[2];
  const float* sw       = (const float*)d_in[3];
  const float* sb       = (const float*)d_in[4];
  const float* dw       = (const float*)d_in[5];
  const float* db       = (const float*)d_in[6];
  const float* decw     = (const float*)d_in[7];
  const float* decb     = (const float*)d_in[8];
  const float* wih      = (const float*)d_in[9];
  const float* whh      = (const float*)d_in[10];
  const float* bih      = (const float*)d_in[11];
  const float* bhh      = (const float*)d_in[12];
  const float* attn_v   = (const float*)d_in[13];
  const float* attn_W   = (const float*)d_in[14];
  const float* ptr_v    = (const float*)d_in[15];
  const float* ptr_W    = (const float*)d_in[16];
  float* ws  = (float*)d_ws;
  float* out = (float*)d_out;

  hipLaunchKernelGGL(prep_small, dim3(2), dim3(256), 0, stream,
                     wih, decw, decb, bih, ws);
  hipLaunchKernelGGL(prep_big, dim3(1024), dim3(256), 0, stream,
                     statics, dynamics, sw, sb, dw, db, attn_W, ptr_W, ws);
  hipLaunchKernelGGL(drl4tsp_main, dim3(128), dim3(512), 0, stream,
                     statics, x0, whh, attn_W, bhh, attn_v, ptr_v, ws, out);
}

// Round 15
// 194.000 us; speedup vs baseline: 1.0203x; 1.0203x over previous
//
#include <hip/hip_runtime.h>
#include <math.h>

// Problem dims (fixed): B=128, S=64, H=128, STATIC=DYNAMIC=2
// Outputs: tour_idx [B,S] (as f32), tour_logp [B,S] -> d_out 16384 f32
//
// FINAL (round-15 = round-13 revert): best verified config.
// 1752us (r1) -> 194us: batch-parallel blocks, step-invariant algebra hoisted
// (GRU input path folded to 2-col matvec; attn/ptr W-products precomputed as
// exp-transformed score bases), whh/Q register-resident (512thr = the shape
// with a real 128-VGPR grant), W3/EA/EP in LDS with position-exact bank
// rotations, DPP-only reductions, lgkm-only barriers, no libm in the loop.
// Round-14's further remap regressed (conflicts 2.5M->6.4M) -> reverted;
// structure declared at practical floor (serial 6-phase recurrence).

#define K1  1.44269504088896340736f   // log2(e)
#define K2  2.88539008177792681472f   // 2*log2(e)
#define LN2 0.69314718055994530942f

// ---------------- ws layout (float offsets) ----------------
#define WS_M     0                       // [384][2]   M = wih @ decoder_w
#define WS_C     768                     // [384]      c = wih @ decoder_b + bih
#define WS_PREA  1152                    // [B][128][64] EA = exp2(K2*(W1@sh + W2@dh))
#define WS_PREP  (WS_PREA + 128*8192)    // [B][128][64] EP = exp2(K2*(P1@sh))
#define WS_Q     (WS_PREP + 128*8192)    // [B][128][64] Q  = P2@sh

// ---- DPP cross-lane (VALU-speed) ----
template <int CTRL>
__device__ __forceinline__ float dppk(float x) {  // bound_ctrl=0: keep self
  int xi = __builtin_bit_cast(int, x);
  return __builtin_bit_cast(float,
      __builtin_amdgcn_update_dpp(xi, xi, CTRL, 0xF, 0xF, false));
}
template <int CTRL>
__device__ __forceinline__ float dppz(float x) {  // bound_ctrl=1: zero-fill
  int xi = __builtin_bit_cast(int, x);
  return __builtin_bit_cast(float,
      __builtin_amdgcn_update_dpp(0, xi, CTRL, 0xF, 0xF, true));
}
__device__ __forceinline__ float bcastf(float x, int lane) {
  return __builtin_bit_cast(float,
      __builtin_amdgcn_readlane(__builtin_bit_cast(int, x), lane));
}
// 0xB1=quad xor1, 0x4E=quad xor2, 0x141=row_half_mirror
__device__ __forceinline__ float sum4(float x) {
  x += dppk<0xB1>(x); x += dppk<0x4E>(x); return x;
}
__device__ __forceinline__ float sum8(float x) {
  x += dppk<0xB1>(x); x += dppk<0x4E>(x); x += dppk<0x141>(x); return x;
}
// wave64 prefix reductions (row_shr + row_bcast + readlane, zero LDS)
__device__ __forceinline__ float wsum64(float x) {
  x += dppz<0x111>(x); x += dppz<0x112>(x); x += dppz<0x114>(x);
  x += dppz<0x118>(x); x += dppz<0x142>(x); x += dppz<0x143>(x);
  return bcastf(x, 63);
}
__device__ __forceinline__ float wmax64(float x) {
  x = fmaxf(x, dppk<0x111>(x)); x = fmaxf(x, dppk<0x112>(x));
  x = fmaxf(x, dppk<0x114>(x)); x = fmaxf(x, dppk<0x118>(x));
  x = fmaxf(x, dppk<0x142>(x)); x = fmaxf(x, dppk<0x143>(x));
  return bcastf(x, 63);
}
#define RCP(x)  __builtin_amdgcn_rcpf(x)
#define EXP2(x) __builtin_amdgcn_exp2f(x)

// lgkm-only barrier: LDS producer/consumer correctness WITHOUT the vmcnt(0)
// drain __syncthreads() emits (in-flight global loads/stores keep flowing).
__device__ __forceinline__ void bar_lds() {
  asm volatile("s_waitcnt lgkmcnt(0)" ::: "memory");
  __builtin_amdgcn_s_barrier();
  asm volatile("" ::: "memory");
}

// bijective bank-rotation for pair-granule index p
__device__ __forceinline__ int rot8(int p) {
  return (p & 56) | ((p + (p >> 3)) & 7);
}

// ---------------- tiny precompute: GRU input-path folding ----------------
__global__ __launch_bounds__(256) void prep_small(
    const float* __restrict__ wih, const float* __restrict__ decw,
    const float* __restrict__ decb, const float* __restrict__ bih,
    float* __restrict__ ws) {
  int gid = blockIdx.x * 256 + threadIdx.x;
  if (gid < 384) {
    float m0 = 0.f, m1 = 0.f, cc = 0.f;
    for (int k = 0; k < 128; ++k) {
      float w = wih[gid * 128 + k];
      m0 += w * decw[k * 2 + 0];
      m1 += w * decw[k * 2 + 1];
      cc += w * decb[k];
    }
    ws[WS_M + gid * 2 + 0] = m0;
    ws[WS_M + gid * 2 + 1] = m1;
    ws[WS_C + gid] = cc + bih[gid];
  }
}

// ---------------- big precompute: EA / EP / Q per batch ------------------
__global__ __launch_bounds__(256) void prep_big(
    const float* __restrict__ statics, const float* __restrict__ dynamics,
    const float* __restrict__ sw, const float* __restrict__ sb,
    const float* __restrict__ dw, const float* __restrict__ db,
    const float* __restrict__ attn_W, const float* __restrict__ ptr_W,
    float* __restrict__ ws) {
  __shared__ __align__(16) float sh[128 * 64];
  __shared__ __align__(16) float dh[128 * 64];
  __shared__ float st[128];
  __shared__ float dy[128];
  int b = blockIdx.x >> 3;
  int hq = blockIdx.x & 7;
  int t = threadIdx.x;
  if (t < 128) st[t] = statics[b * 128 + t];
  else         dy[t - 128] = dynamics[b * 128 + (t - 128)];
  __syncthreads();
  for (int e = t; e < 8192; e += 256) {
    int h = e >> 6, s = e & 63;
    sh[e] = sw[h * 2 + 0] * st[s] + sw[h * 2 + 1] * st[64 + s] + sb[h];
    dh[e] = dw[h * 2 + 0] * dy[s] + dw[h * 2 + 1] * dy[64 + s] + db[h];
  }
  __syncthreads();
  int hh = hq * 16 + (t >> 4);
  int s0 = (t & 15) * 4;
  float4 pA = {0, 0, 0, 0}, pP = {0, 0, 0, 0}, qq = {0, 0, 0, 0};
  for (int k = 0; k < 128; ++k) {
    float4 sv = *(const float4*)&sh[k * 64 + s0];
    float4 dv = *(const float4*)&dh[k * 64 + s0];
    float w1 = attn_W[hh * 384 + k];
    float w2 = attn_W[hh * 384 + 128 + k];
    float p1 = ptr_W[hh * 256 + k];
    float p2 = ptr_W[hh * 256 + 128 + k];
    pA.x += w1 * sv.x + w2 * dv.x;  pA.y += w1 * sv.y + w2 * dv.y;
    pA.z += w1 * sv.z + w2 * dv.z;  pA.w += w1 * sv.w + w2 * dv.w;
    pP.x += p1 * sv.x;  pP.y += p1 * sv.y;  pP.z += p1 * sv.z;  pP.w += p1 * sv.w;
    qq.x += p2 * sv.x;  qq.y += p2 * sv.y;  qq.z += p2 * sv.z;  qq.w += p2 * sv.w;
  }
  // store exp-transformed score bases (shared-exp tanh trick)
  float4 eA, eP;
  eA.x = exp2f(K2 * pA.x); eA.y = exp2f(K2 * pA.y);
  eA.z = exp2f(K2 * pA.z); eA.w = exp2f(K2 * pA.w);
  eP.x = exp2f(K2 * pP.x); eP.y = exp2f(K2 * pP.y);
  eP.z = exp2f(K2 * pP.z); eP.w = exp2f(K2 * pP.w);
  int o = b * 8192 + hh * 64 + s0;
  *(float4*)&ws[WS_PREA + o] = eA;
  *(float4*)&ws[WS_PREP + o] = eP;
  *(float4*)&ws[WS_Q + o]    = qq;
}

// ---------------- main recurrence: 1 block/batch, 512 thr, 64 steps -----
// Best verified config (round-13): W3 bank rotation g->2g makes every
// in-loop LDS access <=2 lanes/position (2-way is free, m136).
__global__ __launch_bounds__(512)
__attribute__((amdgpu_waves_per_eu(2)))
void drl4tsp_main(
    const float* __restrict__ statics, const float* __restrict__ x0,
    const float* __restrict__ whh, const float* __restrict__ attn_W,
    const float* __restrict__ bhh_g, const float* __restrict__ attn_v,
    const float* __restrict__ ptr_v, const float* __restrict__ ws,
    float* __restrict__ out) {
  __shared__ float4 W3s4[128 * 32];   // 64KB [g][(j+2g)&31]
  __shared__ float4 EAT4[64 * 32];    // 32KB [s][(gi+s)&31] (transposed)
  __shared__ float4 EPT4[64 * 32];    // 32KB
  __shared__ float4 uav3[64];         // {u3f,av2} pairs @ rot8(p)
  __shared__ float4 uav2[64];         // {u2f,pv2} pairs @ rot8(p)
  __shared__ float4 gp4[128 * 3];     // 6KB gate params
  __shared__ __align__(16) float hp[144];     // h padded: [k>>5]*36 + (k&31)
  __shared__ __align__(16) float attns[64];   // shared e-buffer
  __shared__ float a_lds[64];
  __shared__ float l_lds[64];
  __shared__ float stt[128];
  __shared__ float outbuf[64];        // per-step argmax idx
  __shared__ float Lhist[4096];       // 16KB: logits archive [step][s]

  const int b    = blockIdx.x;
  const int t    = threadIdx.x;
  const int lane = t & 63;
  const int g    = t >> 2;   // 0..127 row (matvec map, 4-lane groups)
  const int q    = t & 3;    // k/s quarter
  const int s    = t >> 3;   // 0..63 column (score map, 8-lane groups)
  const int hg   = t & 7;    // h-group of 16

  // ---- register weights: whh rows, interleaved k-map (k = kk*16+q*4+j) ----
  float wr0[32], wr1[32], wr2[32];
#pragma unroll
  for (int kk = 0; kk < 8; ++kk) {
    float4 a = *(const float4*)(whh + g * 128         + kk * 16 + q * 4);
    float4 c = *(const float4*)(whh + (128 + g) * 128 + kk * 16 + q * 4);
    float4 d = *(const float4*)(whh + (256 + g) * 128 + kk * 16 + q * 4);
    wr0[4*kk] = a.x; wr0[4*kk+1] = a.y; wr0[4*kk+2] = a.z; wr0[4*kk+3] = a.w;
    wr1[4*kk] = c.x; wr1[4*kk+1] = c.y; wr1[4*kk+2] = c.z; wr1[4*kk+3] = c.w;
    wr2[4*kk] = d.x; wr2[4*kk+1] = d.y; wr2[4*kk+2] = d.z; wr2[4*kk+3] = d.w;
  }
  float qr[16];
  {
    const float4* pq = (const float4*)(ws + WS_Q + b * 8192 + g * 64 + q * 16);
#pragma unroll
    for (int i = 0; i < 4; ++i) {
      float4 v = pq[i];
      qr[4*i] = v.x; qr[4*i+1] = v.y; qr[4*i+2] = v.z; qr[4*i+3] = v.w;
    }
  }

  // ---- LDS init ----
  {  // W3 row g, granule j stored at (j+2g)&31 (2-way-free rotation)
    const float4* src = (const float4*)(attn_W + g * 384 + 256);
#pragma unroll
    for (int kk = 0; kk < 8; ++kk) {
      int j = q * 8 + kk;
      W3s4[g * 32 + ((j + 2 * g) & 31)] = src[j];
    }
  }
  for (int e = t; e < 8192; e += 512) {  // EA/EP transpose + s-rotation
    int h = e >> 6, sE = e & 63;
    int rg = ((h >> 2) + sE) & 31;
    ((float*)EAT4)[sE * 128 + rg * 4 + (h & 3)] = ws[WS_PREA + b * 8192 + e];
    ((float*)EPT4)[sE * 128 + rg * 4 + (h & 3)] = ws[WS_PREP + b * 8192 + e];
  }
  if (t < 128) {
    int h = t;
    int rg = rot8(h >> 1);
    ((float*)uav3)[rg * 4 + (h & 1) * 2 + 1] = 2.0f * attn_v[h];
    ((float*)uav2)[rg * 4 + (h & 1) * 2 + 1] = 2.0f * ptr_v[h];
    stt[h] = statics[b * 128 + h];
    const float* Mm = ws + WS_M;
    const float* Cc = ws + WS_C;
    float cR = Cc[h] + bhh_g[h];
    float cZ = Cc[128 + h] + bhh_g[128 + h];
    gp4[h*3 + 0] = float4{Mm[h*2], Mm[h*2+1], cR, Mm[(128+h)*2]};
    gp4[h*3 + 1] = float4{Mm[(128+h)*2+1], cZ, Mm[(256+h)*2], Mm[(256+h)*2+1]};
    gp4[h*3 + 2] = float4{Cc[256+h], bhh_g[256+h], 0.f, 0.f};
  }
  __syncthreads();

  float hreg = 0.f, ghr = 0.f, ghz = 0.f, ghn = 0.f;
  float d0 = x0[0], d1 = x0[1];

  for (int step = 0; step < 64; ++step) {
    // ---- P1: GRU gates (pointwise; gh carried from prev step) ----
    {
      float4 v0 = gp4[g*3], v1 = gp4[g*3+1], v2 = gp4[g*3+2];
      float r = RCP(1.f + EXP2(-K1 * (v0.x*d0 + v0.y*d1 + v0.z + ghr)));
      float z = RCP(1.f + EXP2(-K1 * (v0.w*d0 + v1.x*d1 + v1.y + ghz)));
      float xn = v1.z*d0 + v1.w*d1 + v2.x + r * (ghn + v2.y);
      float n = 1.f - 2.f * RCP(EXP2(K2 * xn) + 1.f);   // tanh(xn)
      hreg = (1.f - z) * n + z * hreg;
      if (q == 0) hp[(g >> 5) * 36 + (g & 31)] = hreg;
    }
    bar_lds();                                         // A
    // ---- PB: u3 = W3@h only (gh matvec deferred to C/D windows) ----
    {
      float u3a = 0.f, u3b = 0.f;
#pragma unroll
      for (int kk = 0; kk < 8; ++kk) {
        float4 hv = *(const float4*)&hp[(kk >> 1) * 36 + (kk & 1) * 16 + q * 4];
        float4 wv = W3s4[g * 32 + ((kk * 4 + q + 2 * g) & 31)];
        float d2 = wv.x*hv.x + wv.y*hv.y + wv.z*hv.z + wv.w*hv.w;
        if (kk & 1) u3b += d2; else u3a += d2;
      }
      float u3 = sum4(u3a + u3b);
      if (q == 0)
        ((float*)uav3)[rot8(g >> 1) * 4 + (g & 1) * 2] = EXP2(K2 * u3);
    }
    bar_lds();                                         // B
    float sr = 0.f, sz = 0.f, sn = 0.f;   // gh partials, finalized in PD
    // ---- PC: attn scores (paired rcp) + gh kk=0..3 (independent fill) --
    {
      float acc0 = 0.f, acc1 = 0.f;
#pragma unroll
      for (int ii = 0; ii < 4; ++ii) {
        float4 ea = EAT4[s * 32 + ((hg * 4 + ii + s) & 31)];
        int p0 = hg * 8 + 2 * ii;
        float4 ua = uav3[(p0 & 56) | ((p0 + hg) & 7)];
        float4 ub = uav3[((p0+1) & 56) | ((p0 + 1 + hg) & 7)];
        float x1 = ea.x * ua.x + 1.f, y1 = ea.y * ua.z + 1.f;
        acc0 += (ua.y * y1 + ua.w * x1) * RCP(x1 * y1);
        float x2 = ea.z * ub.x + 1.f, y2 = ea.w * ub.z + 1.f;
        acc1 += (ub.y * y2 + ub.w * x2) * RCP(x2 * y2);
      }
#pragma unroll
      for (int kk = 0; kk < 4; ++kk) {
        float4 hv = *(const float4*)&hp[(kk >> 1) * 36 + (kk & 1) * 16 + q * 4];
        int k = kk * 4;
        sr += wr0[k]*hv.x + wr0[k+1]*hv.y + wr0[k+2]*hv.z + wr0[k+3]*hv.w;
        sz += wr1[k]*hv.x + wr1[k+1]*hv.y + wr1[k+2]*hv.z + wr1[k+3]*hv.w;
        sn += wr2[k]*hv.x + wr2[k+1]*hv.y + wr2[k+2]*hv.z + wr2[k+3]*hv.w;
      }
      float acc = sum8(acc0 + acc1);
      if (hg == 0) a_lds[s] = -acc;
    }
    bar_lds();                                         // C
    // ---- PD: softmax (no max-shift) + u2 = Q@attns + gh kk=4..7
    //          + EPT prefetch for PE (issued under the softmax chain) ----
    float4 ep0, ep1, ep2, ep3;
    {
      float a = a_lds[lane];
      ep0 = EPT4[s * 32 + ((hg * 4 + 0 + s) & 31)];   // prefetch (indep.)
      ep1 = EPT4[s * 32 + ((hg * 4 + 1 + s) & 31)];
      ep2 = EPT4[s * 32 + ((hg * 4 + 2 + s) & 31)];
      ep3 = EPT4[s * 32 + ((hg * 4 + 3 + s) & 31)];
      float e = EXP2(K1 * a);          // |a| <~ 20 -> range-safe in f32
      attns[lane] = e;                 // identical writes from all waves
#pragma unroll
      for (int kk = 4; kk < 8; ++kk) { // fill attns write->read latency
        float4 hv = *(const float4*)&hp[(kk >> 1) * 36 + (kk & 1) * 16 + q * 4];
        int k = kk * 4;
        sr += wr0[k]*hv.x + wr0[k+1]*hv.y + wr0[k+2]*hv.z + wr0[k+3]*hv.w;
        sz += wr1[k]*hv.x + wr1[k+1]*hv.y + wr1[k+2]*hv.z + wr1[k+3]*hv.w;
        sn += wr2[k]*hv.x + wr2[k+1]*hv.y + wr2[k+2]*hv.z + wr2[k+3]*hv.w;
      }
      float sum = wsum64(e);           // all-DPP prefix + readlane (uniform)
      float p = 0.f;
#pragma unroll
      for (int ii = 0; ii < 4; ++ii) {
        float4 av = *(const float4*)&attns[q * 16 + ii * 4];
        p += qr[4*ii]*av.x + qr[4*ii+1]*av.y + qr[4*ii+2]*av.z + qr[4*ii+3]*av.w;
      }
      p *= RCP(sum);
      p = sum4(p);
      if (q == 0)
        ((float*)uav2)[rot8(g >> 1) * 4 + (g & 1) * 2] = EXP2(K2 * p);
      ghr = sum4(sr); ghz = sum4(sz); ghn = sum4(sn);
    }
    bar_lds();                                         // D
    // ---- PE: ptr logits (paired rcp, EPT prefetched) ----
    {
      float acc0 = 0.f, acc1 = 0.f;
#pragma unroll
      for (int ii = 0; ii < 4; ++ii) {
        float4 ep = (ii == 0) ? ep0 : (ii == 1) ? ep1 : (ii == 2) ? ep2 : ep3;
        int p0 = hg * 8 + 2 * ii;
        float4 ua = uav2[(p0 & 56) | ((p0 + hg) & 7)];
        float4 ub = uav2[((p0+1) & 56) | ((p0 + 1 + hg) & 7)];
        float x1 = ep.x * ua.x + 1.f, y1 = ep.y * ua.z + 1.f;
        acc0 += (ua.y * y1 + ua.w * x1) * RCP(x1 * y1);
        float x2 = ep.z * ub.x + 1.f, y2 = ep.w * ub.z + 1.f;
        acc1 += (ub.y * y2 + ub.w * x2) * RCP(x2 * y2);
      }
      float acc = sum8(acc0 + acc1);
      if (hg == 0) l_lds[s] = -acc;
    }
    bar_lds();                                         // E
    // ---- P6: argmax only (logp deferred); DPP max + ballot/ctz ----
    {
      float L = l_lds[lane];
      float v = wmax64(L);                        // uniform via readlane
      unsigned long long mk = __ballot(L == v);   // exact bit-compare
      int idx = __builtin_ctzll(mk);              // lowest lane = lowest s
      if (t < 64) Lhist[step * 64 + t] = L;       // archive for logp pass
      if (t == 0) outbuf[step] = (float)idx;
      d0 = stt[idx];                              // uniform broadcast
      d1 = stt[64 + idx];
    }
    // no barrier: every buffer's next write is >=2 barrier-phases away
  }
  bar_lds();
  // ---- epilogue: all 64 log-softmax values in parallel (8 waves x 8) ----
  {
    int wv = t >> 6;
    for (int st = wv; st < 64; st += 8) {
      float L = Lhist[st * 64 + lane];
      float v = wmax64(L);
      float e2 = EXP2(K1 * (L - v));
      float s3 = wsum64(e2);
      if (lane == 0)
        out[8192 + b * 64 + st] = -LN2 * __builtin_amdgcn_logf(s3);
      if (lane == 1)
        out[b * 64 + st] = outbuf[st];
    }
  }
}

extern "C" void kernel_launch(void* const* d_in, const int* in_sizes, int n_in,
                              void* d_out, int out_size, void* d_ws, size_t ws_size,
                              hipStream_t stream) {
  const float* statics  = (const float*)d_in[0];
  const float* dynamics = (const float*)d_in[1];
  const float* x0       = (const float*)d_in[2];
  const float* sw       = (const float*)d_in[3];
  const float* sb       = (const float*)d_in[4];
  const float* dw       = (const float*)d_in[5];
  const float* db       = (const float*)d_in[6];
  const float* decw     = (const float*)d_in[7];
  const float* decb     = (const float*)d_in[8];
  const float* wih      = (const float*)d_in[9];
  const float* whh      = (const float*)d_in[10];
  const float* bih      = (const float*)d_in[11];
  const float* bhh      = (const float*)d_in[12];
  const float* attn_v   = (const float*)d_in[13];
  const float* attn_W   = (const float*)d_in[14];
  const float* ptr_v    = (const float*)d_in[15];
  const float* ptr_W    = (const float*)d_in[16];
  float* ws  = (float*)d_ws;
  float* out = (float*)d_out;

  hipLaunchKernelGGL(prep_small, dim3(2), dim3(256), 0, stream,
                     wih, decw, decb, bih, ws);
  hipLaunchKernelGGL(prep_big, dim3(1024), dim3(256), 0, stream,
                     statics, dynamics, sw, sb, dw, db, attn_W, ptr_W, ws);
  hipLaunchKernelGGL(drl4tsp_main, dim3(128), dim3(512), 0, stream,
                     statics, x0, whh, attn_W, bhh, attn_v, ptr_v, ws, out);
}